// Round 8
// baseline (343.732 us; speedup 1.0000x reference)
//
#include <hip/hip_runtime.h>
#include <hip/hip_bf16.h>

typedef unsigned short u16;
typedef __attribute__((ext_vector_type(8))) short short8;
typedef __attribute__((ext_vector_type(4))) float floatx4;

// ---------- helpers ----------
__device__ __forceinline__ u16 f2bf(float f) {
    union { float f; unsigned u; } v; v.f = f;
    unsigned r = v.u + 0x7fffu + ((v.u >> 16) & 1u);   // RNE
    return (u16)(r >> 16);
}
__device__ __forceinline__ float fexp2(float x) {
#if __has_builtin(__builtin_amdgcn_exp2f)
    return __builtin_amdgcn_exp2f(x);
#else
    return exp2f(x);
#endif
}

// async global->LDS, 16B per lane. LDS dest = wave-uniform base + lane*16.
__device__ __forceinline__ void async_load16(const void* g, void* l) {
    __builtin_amdgcn_global_load_lds(
        (const __attribute__((address_space(1))) unsigned int*)g,
        (__attribute__((address_space(3))) unsigned int*)l, 16, 0, 0);
}

#define B_   4
#define T_   2048
#define NH_  16
#define HD_  64
#define DIM_ 1024
#define M_   (B_ * T_)          // 8192
#define NQKV (3 * DIM_)         // 3072
#define LOG2E 1.4426950408889634f

// ---------- fp32 -> bf16 elementwise (x) ----------
__global__ void cvt_x(const float* __restrict__ in, u16* __restrict__ out) {
    int idx = blockIdx.x * 256 + threadIdx.x;          // one float4 per thread
    float4 v = ((const float4*)in)[idx];
    ushort4 o;
    o.x = f2bf(v.x); o.y = f2bf(v.y); o.z = f2bf(v.z); o.w = f2bf(v.w);
    ((ushort4*)out)[idx] = o;
}

// ---------- fp32 [R][Cn] -> bf16 [Cn][R] transpose ----------
__global__ void transpose_cvt(const float* __restrict__ in, u16* __restrict__ out,
                              int R, int Cn) {
    __shared__ float tile[32][33];
    int c0 = blockIdx.x * 32, r0 = blockIdx.y * 32;
    int tx = threadIdx.x, ty = threadIdx.y;            // 32 x 8
#pragma unroll
    for (int i = 0; i < 4; ++i)
        tile[ty + i * 8][tx] = in[(size_t)(r0 + ty + i * 8) * Cn + c0 + tx];
    __syncthreads();
#pragma unroll
    for (int i = 0; i < 4; ++i)
        out[(size_t)(c0 + ty + i * 8) * R + r0 + tx] = f2bf(tile[tx][ty + i * 8]);
}

// ---------- RoPE tables (fp64 once, tiny) ----------
__global__ void rope_table(float* __restrict__ tabc, float* __restrict__ tabs) {
    int idx = blockIdx.x * 256 + threadIdx.x;
    if (idx >= T_ * 32) return;
    int t = idx >> 5, j = idx & 31;
    double invf = pow(10000.0, -(double)j / 32.0);
    double th = (double)t * invf;
    tabc[idx] = (float)cos(th);
    tabs[idx] = (float)sin(th);
}

// ---------- V transpose: Vh[m][d1024] -> Vt[bh][d][t] ----------
__global__ void v_transpose(const u16* __restrict__ Vh, u16* __restrict__ Vt) {
    __shared__ u16 tile[64 * 68];                      // row stride 68 u16 = 136 B
    const int tid = threadIdx.x;
    const int bh = blockIdx.y, b = bh >> 4, h = bh & 15;
    const int t0 = blockIdx.x * 64;
    {
        int lr = tid >> 2;                             // t-row 0..63
        int lc = tid & 3;
        const u16* src = Vh + ((size_t)(b * T_ + t0 + lr)) * DIM_ + h * HD_;
#pragma unroll
        for (int j = 0; j < 4; ++j) {
            int c = (lc + j * 4) * 4;                  // u16 col, 8B chunks
            *(uint2*)&tile[lr * 68 + c] = *(const uint2*)(src + c);
        }
    }
    __syncthreads();
    {
        int d2 = tid >> 3, tseg = tid & 7;             // dword col 0..31, t-seg 0..7
        u16 lo8[8], hi8[8];
#pragma unroll
        for (int j = 0; j < 8; ++j) {
            unsigned w = *(const unsigned*)&tile[(tseg * 8 + j) * 68 + d2 * 2];
            lo8[j] = (u16)(w & 0xffffu);
            hi8[j] = (u16)(w >> 16);
        }
        size_t ob = ((size_t)bh * HD_ + 2 * d2) * T_ + t0 + tseg * 8;
        *(uint4*)(Vt + ob) = *(const uint4*)lo8;
        *(uint4*)(Vt + ob + T_) = *(const uint4*)hi8;
    }
}

// ---------- qkv GEMM, m-tile PAIRED (zero dispatch tail), fused RoPE/split ----
// Grid (24, 32): block does m-tiles {by, by+32} with the same n0 (B-tile L2
// reuse). 768 blocks = 3/CU, all co-resident, uniform work -> no tail epoch
// (1536-block grid left 512 blocks running at 50% fill: 81us, MfmaUtil 26%).
// Epilogue routes the tile through LDS (padded stride 136 u16) -> coalesced
// dwordx4 stores.
__global__ __launch_bounds__(256) void gemm_qkv(const u16* __restrict__ A,
                                                const u16* __restrict__ Bt,
                                                const float* __restrict__ tabc,
                                                const float* __restrict__ tabs,
                                                u16* __restrict__ Qo,
                                                u16* __restrict__ Ko,
                                                u16* __restrict__ Vh) {
    __shared__ __align__(16) u16 smem[128 * 136];      // Asl|Bsl (16K) / Es 128x136
    u16* Asl = smem;
    u16* Bsl = smem + 128 * 64;
    const int tid = threadIdx.x;
    const int wave = tid >> 6, lane = tid & 63;
    const int ln15 = lane & 15, quad = lane >> 4;
    const int n0 = blockIdx.x * 128;
    const int wm = (wave & 1) * 64, wn = (wave >> 1) * 64;
    const int l8 = lane & 7, ld8 = lane >> 3;
    const int sgc = (l8 ^ ld8) * 8;                    // swizzled source col (u16)
    const int K = DIM_;
    const int sel = n0 >> 10;                          // 0=q, 1=k, 2=v

#pragma unroll 1
    for (int half = 0; half < 2; ++half) {
        const int m0 = (blockIdx.y + half * 32) * 128;

        floatx4 acc[4][4] = {};

        for (int k0 = 0; k0 < K; k0 += 64) {
#pragma unroll
            for (int it = 0; it < 4; ++it) {
                int rb = wave * 32 + it * 8;
                async_load16(A  + (size_t)(m0 + rb + ld8) * K + k0 + sgc, &Asl[rb * 64]);
                async_load16(Bt + (size_t)(n0 + rb + ld8) * K + k0 + sgc, &Bsl[rb * 64]);
            }
            __syncthreads();
#pragma unroll
            for (int kk = 0; kk < 64; kk += 32) {
                const int c4 = kk >> 3;                // 0 or 4
                short8 af[4], bfm[4];
#pragma unroll
                for (int i = 0; i < 4; ++i) {
                    int row = wm + i * 16 + ln15;
                    af[i] = *(const short8*)&Asl[row * 64 + (((c4 + quad) ^ (row & 7)) << 3)];
                }
#pragma unroll
                for (int jj = 0; jj < 4; ++jj) {
                    int row = wn + jj * 16 + ln15;
                    bfm[jj] = *(const short8*)&Bsl[row * 64 + (((c4 + quad) ^ (row & 7)) << 3)];
                }
#pragma unroll
                for (int i = 0; i < 4; ++i)
#pragma unroll
                    for (int jj = 0; jj < 4; ++jj)
                        acc[i][jj] = __builtin_amdgcn_mfma_f32_16x16x32_bf16(
                            af[i], bfm[jj], acc[i][jj], 0, 0, 0);
            }
            __syncthreads();
        }

        // ---- epilogue: acc -> Es (bf16, padded rows) -> coalesced stores ----
        u16* Es = smem;
        if (sel == 2) {
#pragma unroll
            for (int i = 0; i < 4; ++i)
#pragma unroll
                for (int jj = 0; jj < 4; ++jj)
#pragma unroll
                    for (int r = 0; r < 4; ++r)
                        Es[(wm + i * 16 + quad * 4 + r) * 136 + wn + jj * 16 + ln15] =
                            f2bf(acc[i][jj][r]);
        } else {
            const float scale = sel ? 1.0f : 0.125f * LOG2E;
#pragma unroll
            for (int i = 0; i < 4; ++i)
#pragma unroll
                for (int jjl = 0; jjl < 2; ++jjl) {
                    int j = jjl * 16 + ln15;           // d in [0,32)
#pragma unroll
                    for (int r = 0; r < 4; ++r) {
                        int row = wm + i * 16 + quad * 4 + r;
                        int t = (m0 + row) & (T_ - 1);
                        float cs = tabc[t * 32 + j], sn = tabs[t * 32 + j];
                        float xl = acc[i][jjl][r], xh = acc[i][jjl + 2][r];
                        Es[row * 136 + wn + j]      = f2bf((xl * cs - xh * sn) * scale);
                        Es[row * 136 + wn + j + 32] = f2bf((xh * cs + xl * sn) * scale);
                    }
                }
        }
        __syncthreads();
        const int bb = m0 >> 11;
        u16* outqk = (sel == 1) ? Ko : Qo;
#pragma unroll
        for (int k = 0; k < 8; ++k) {
            int cid = tid + k * 256;                   // 0..2047
            int row = cid >> 4, c = cid & 15;          // chunk 0..15
            uint4 v = *(const uint4*)&Es[row * 136 + c * 8];
            if (sel == 2) {
                *(uint4*)&Vh[(size_t)(m0 + row) * DIM_ + (n0 & 1023) + c * 8] = v;
            } else {
                int h = ((n0 & 1023) >> 6) + (c >> 3);
                int d = (c & 7) * 8;
                int t = (m0 + row) & (T_ - 1);
                *(uint4*)&outqk[((size_t)(bb * NH_ + h) * T_ + t) * HD_ + d] = v;
            }
        }
        __syncthreads();                               // Es free before next half
    }
}

// ---------- generic 128x128 GEMM (used for out-proj), swizzled LDS ----------
__global__ __launch_bounds__(256) void gemm_bt_f32(const u16* __restrict__ A,
                                                   const u16* __restrict__ Bt,
                                                   float* __restrict__ C,
                                                   int M, int N, int K) {
    __shared__ __align__(16) u16 Asl[128 * 64];
    __shared__ __align__(16) u16 Bsl[128 * 64];
    const int tid = threadIdx.x;
    const int wave = tid >> 6, lane = tid & 63;
    const int ln15 = lane & 15, quad = lane >> 4;
    const int m0 = blockIdx.y * 128, n0 = blockIdx.x * 128;
    const int wm = (wave & 1) * 64, wn = (wave >> 1) * 64;
    const int l8 = lane & 7, ld8 = lane >> 3;
    const int sgc = (l8 ^ ld8) * 8;

    floatx4 acc[4][4] = {};

    for (int k0 = 0; k0 < K; k0 += 64) {
#pragma unroll
        for (int it = 0; it < 4; ++it) {
            int rb = wave * 32 + it * 8;
            async_load16(A  + (size_t)(m0 + rb + ld8) * K + k0 + sgc, &Asl[rb * 64]);
            async_load16(Bt + (size_t)(n0 + rb + ld8) * K + k0 + sgc, &Bsl[rb * 64]);
        }
        __syncthreads();
#pragma unroll
        for (int kk = 0; kk < 64; kk += 32) {
            const int c4 = kk >> 3;
            short8 af[4], bfm[4];
#pragma unroll
            for (int i = 0; i < 4; ++i) {
                int row = wm + i * 16 + ln15;
                af[i] = *(const short8*)&Asl[row * 64 + (((c4 + quad) ^ (row & 7)) << 3)];
            }
#pragma unroll
            for (int jj = 0; jj < 4; ++jj) {
                int row = wn + jj * 16 + ln15;
                bfm[jj] = *(const short8*)&Bsl[row * 64 + (((c4 + quad) ^ (row & 7)) << 3)];
            }
#pragma unroll
            for (int i = 0; i < 4; ++i)
#pragma unroll
                for (int jj = 0; jj < 4; ++jj)
                    acc[i][jj] = __builtin_amdgcn_mfma_f32_16x16x32_bf16(
                        af[i], bfm[jj], acc[i][jj], 0, 0, 0);
        }
        __syncthreads();
    }
#pragma unroll
    for (int i = 0; i < 4; ++i)
#pragma unroll
        for (int jj = 0; jj < 4; ++jj)
#pragma unroll
            for (int r = 0; r < 4; ++r) {
                int m = m0 + wm + i * 16 + quad * 4 + r;
                int n = n0 + wn + jj * 16 + ln15;
                C[(size_t)m * N + n] = acc[i][jj][r];
            }
}

// ---------- flash attention, uniform-work pairing, no-max softmax, dbuf K/V ----
__global__ __launch_bounds__(256, 4) void attn_kernel(const u16* __restrict__ Q,
                                                      const u16* __restrict__ Kh,
                                                      const u16* __restrict__ Vt,
                                                      u16* __restrict__ Y) {
    __shared__ __align__(16) u16 Kl[2][64 * 64];
    __shared__ __align__(16) u16 Vl[2][64 * 64];
    __shared__ __align__(16) u16 Pl[4][16 * 64];
    const int tid = threadIdx.x, wave = tid >> 6, lane = tid & 63;
    const int ln15 = lane & 15, quad = lane >> 4;
    const int p = blockIdx.x;                          // pair index 0..15
    const int bh = blockIdx.y;
    const int b = bh >> 4, h = bh & 15;
    const int l8 = lane & 7, ld8 = lane >> 3;
    const int sgc = l8 ^ ld8;                          // swizzled source chunk

    const u16* kbase = Kh + (size_t)bh * T_ * HD_;
    const u16* vbase = Vt + (size_t)bh * HD_ * T_;
    const short8 ones = {0x3F80, 0x3F80, 0x3F80, 0x3F80,
                         0x3F80, 0x3F80, 0x3F80, 0x3F80};
    const int srow = wave * 16;

#pragma unroll
    for (int half = 0; half < 2; ++half) {
        const int tidx = half ? p : (31 - p);          // q-tile index 0..31
        const int q0 = tidx * 64;
        const int bm = q0 + srow;

        const u16* qp = Q + ((size_t)bh * T_ + bm + ln15) * HD_;
        short8 qf0 = *(const short8*)(qp + quad * 8);
        short8 qf1 = *(const short8*)(qp + 32 + quad * 8);

        floatx4 o[5] = {};                             // 0..3 = d-cols, 4 = rowsum

        __syncthreads();                               // buffers free from prev half
#pragma unroll
        for (int it = 0; it < 2; ++it) {
            int r = srow + it * 8;
            async_load16(kbase + (size_t)(r + ld8) * HD_ + sgc * 8, &Kl[0][r * 64]);
            async_load16(vbase + (size_t)(r + ld8) * T_ + sgc * 8, &Vl[0][r * 64]);
        }

        for (int kt = 0; kt <= tidx; ++kt) {
            const int cur = kt & 1;
            __syncthreads();                           // publishes tile kt
            if (kt < tidx) {                           // prefetch kt+1 (overlaps)
                const int kn = (kt + 1) * 64;
#pragma unroll
                for (int it = 0; it < 2; ++it) {
                    int r = srow + it * 8;
                    async_load16(kbase + (size_t)(kn + r + ld8) * HD_ + sgc * 8,
                                 &Kl[cur ^ 1][r * 64]);
                    async_load16(vbase + (size_t)(r + ld8) * T_ + kn + sgc * 8,
                                 &Vl[cur ^ 1][r * 64]);
                }
            }
            floatx4 s[4] = {};
#pragma unroll
            for (int nt = 0; nt < 4; ++nt) {
                int row = nt * 16 + ln15;
                short8 kf0 = *(const short8*)&Kl[cur][row * 64 + ((quad ^ (row & 7)) << 3)];
                short8 kf1 = *(const short8*)&Kl[cur][row * 64 + (((4 + quad) ^ (row & 7)) << 3)];
                s[nt] = __builtin_amdgcn_mfma_f32_16x16x32_bf16(qf0, kf0, s[nt], 0, 0, 0);
                s[nt] = __builtin_amdgcn_mfma_f32_16x16x32_bf16(qf1, kf1, s[nt], 0, 0, 0);
            }
            if (kt == tidx) {                          // diagonal tile: causal mask
#pragma unroll
                for (int nt = 0; nt < 4; ++nt) {
                    int key = nt * 16 + ln15, lim = srow + quad * 4;
#pragma unroll
                    for (int r = 0; r < 4; ++r)
                        s[nt][r] = (key > lim + r) ? 0.f : fexp2(s[nt][r]);
                }
            } else {
#pragma unroll
                for (int nt = 0; nt < 4; ++nt)
#pragma unroll
                    for (int r = 0; r < 4; ++r) s[nt][r] = fexp2(s[nt][r]);
            }
            u16* pw = Pl[wave];
#pragma unroll
            for (int nt = 0; nt < 4; ++nt) {
                int kc = nt * 2 + (ln15 >> 3), k7 = ln15 & 7;
#pragma unroll
                for (int r = 0; r < 4; ++r) {
                    int row = quad * 4 + r;
                    pw[row * 64 + ((kc ^ (row & 7)) << 3) + k7] = f2bf(s[nt][r]);
                }
            }
            short8 pf0 = *(const short8*)&pw[ln15 * 64 + ((quad ^ (ln15 & 7)) << 3)];
            short8 pf1 = *(const short8*)&pw[ln15 * 64 + (((4 + quad) ^ (ln15 & 7)) << 3)];
#pragma unroll
            for (int nt = 0; nt < 4; ++nt) {
                int row = nt * 16 + ln15;
                short8 vf0 = *(const short8*)&Vl[cur][row * 64 + ((quad ^ (row & 7)) << 3)];
                short8 vf1 = *(const short8*)&Vl[cur][row * 64 + (((4 + quad) ^ (row & 7)) << 3)];
                o[nt] = __builtin_amdgcn_mfma_f32_16x16x32_bf16(pf0, vf0, o[nt], 0, 0, 0);
                o[nt] = __builtin_amdgcn_mfma_f32_16x16x32_bf16(pf1, vf1, o[nt], 0, 0, 0);
            }
            o[4] = __builtin_amdgcn_mfma_f32_16x16x32_bf16(pf0, ones, o[4], 0, 0, 0);
            o[4] = __builtin_amdgcn_mfma_f32_16x16x32_bf16(pf1, ones, o[4], 0, 0, 0);
        }
#pragma unroll
        for (int r = 0; r < 4; ++r) {
            float inv = 1.f / o[4][r];
            int row = bm + quad * 4 + r;
            u16* yp = Y + ((size_t)(b * T_ + row)) * DIM_ + h * HD_;
#pragma unroll
            for (int nt = 0; nt < 4; ++nt)
                yp[nt * 16 + ln15] = f2bf(o[nt][r] * inv);
        }
    }
}

// ---------- launch ----------
extern "C" void kernel_launch(void* const* d_in, const int* in_sizes, int n_in,
                              void* d_out, int out_size, void* d_ws, size_t ws_size,
                              hipStream_t stream) {
    const float* x     = (const float*)d_in[0];
    const float* Wqkv  = (const float*)d_in[1];
    const float* Wproj = (const float*)d_in[2];
    float* out = (float*)d_out;
    char* ws = (char*)d_ws;

    const size_t SZ_XB  = (size_t)M_ * DIM_ * 2;       // 16 MB
    const size_t SZ_WQT = (size_t)NQKV * DIM_ * 2;     // 6 MB
    const size_t SZ_WPT = (size_t)DIM_ * DIM_ * 2;     // 2 MB
    const size_t SZ_Q   = SZ_XB;                       // 16 MB each: Q,K,Vh,Vt
    const size_t SZ_TAB = (size_t)T_ * 32 * 4;         // 256 KB

    u16*   xb   = (u16*)(ws);
    u16*   wqt  = (u16*)(ws + SZ_XB);
    u16*   wpt  = (u16*)(ws + SZ_XB + SZ_WQT);
    u16*   qb   = (u16*)(ws + SZ_XB + SZ_WQT + SZ_WPT);
    u16*   kb   = (u16*)(ws + SZ_XB + SZ_WQT + SZ_WPT + SZ_Q);
    u16*   vhb  = (u16*)(ws + SZ_XB + SZ_WQT + SZ_WPT + 2 * SZ_Q);
    u16*   vtb  = (u16*)(ws + SZ_XB + SZ_WQT + SZ_WPT + 3 * SZ_Q);
    float* tabc = (float*)(ws + SZ_XB + SZ_WQT + SZ_WPT + 4 * SZ_Q);
    float* tabs = (float*)(ws + SZ_XB + SZ_WQT + SZ_WPT + 4 * SZ_Q + SZ_TAB);
    u16*   yb   = xb;                                  // reuse xb after qkv GEMM

    rope_table<<<(T_ * 32 + 255) / 256, 256, 0, stream>>>(tabc, tabs);
    cvt_x<<<(M_ * DIM_ / 4) / 256, 256, 0, stream>>>(x, xb);
    transpose_cvt<<<dim3(NQKV / 32, DIM_ / 32), dim3(32, 8), 0, stream>>>(Wqkv, wqt, DIM_, NQKV);
    transpose_cvt<<<dim3(DIM_ / 32, DIM_ / 32), dim3(32, 8), 0, stream>>>(Wproj, wpt, DIM_, DIM_);
    gemm_qkv<<<dim3(NQKV / 128, M_ / 128 / 2), 256, 0, stream>>>(xb, wqt, tabc, tabs, qb, kb, vhb);
    v_transpose<<<dim3(T_ / 64, B_ * NH_), 256, 0, stream>>>(vhb, vtb);
    attn_kernel<<<dim3(16, B_ * NH_), 256, 0, stream>>>(qb, kb, vtb, yb);
    gemm_bt_f32<<<dim3(DIM_ / 128, M_ / 128), 256, 0, stream>>>(yb, wpt, out, M_, DIM_, DIM_);
}

// Round 9
// 267.770 us; speedup vs baseline: 1.2837x; 1.2837x over previous
//
#include <hip/hip_runtime.h>
#include <hip/hip_bf16.h>

typedef unsigned short u16;
typedef __attribute__((ext_vector_type(8))) short short8;
typedef __attribute__((ext_vector_type(4))) float floatx4;

// ---------- helpers ----------
__device__ __forceinline__ u16 f2bf(float f) {
    union { float f; unsigned u; } v; v.f = f;
    unsigned r = v.u + 0x7fffu + ((v.u >> 16) & 1u);   // RNE
    return (u16)(r >> 16);
}
__device__ __forceinline__ float fexp2(float x) {
#if __has_builtin(__builtin_amdgcn_exp2f)
    return __builtin_amdgcn_exp2f(x);
#else
    return exp2f(x);
#endif
}

// async global->LDS, 16B per lane. LDS dest = wave-uniform base + lane*16.
__device__ __forceinline__ void async_load16(const void* g, void* l) {
    __builtin_amdgcn_global_load_lds(
        (const __attribute__((address_space(1))) unsigned int*)g,
        (__attribute__((address_space(3))) unsigned int*)l, 16, 0, 0);
}

#define B_   4
#define T_   2048
#define NH_  16
#define HD_  64
#define DIM_ 1024
#define M_   (B_ * T_)          // 8192
#define NQKV (3 * DIM_)         // 3072
#define LOG2E 1.4426950408889634f

// ---------- fp32 -> bf16 elementwise (x) ----------
__global__ void cvt_x(const float* __restrict__ in, u16* __restrict__ out) {
    int idx = blockIdx.x * 256 + threadIdx.x;          // one float4 per thread
    float4 v = ((const float4*)in)[idx];
    ushort4 o;
    o.x = f2bf(v.x); o.y = f2bf(v.y); o.z = f2bf(v.z); o.w = f2bf(v.w);
    ((ushort4*)out)[idx] = o;
}

// ---------- fp32 [R][Cn] -> bf16 [Cn][R] transpose ----------
__global__ void transpose_cvt(const float* __restrict__ in, u16* __restrict__ out,
                              int R, int Cn) {
    __shared__ float tile[32][33];
    int c0 = blockIdx.x * 32, r0 = blockIdx.y * 32;
    int tx = threadIdx.x, ty = threadIdx.y;            // 32 x 8
#pragma unroll
    for (int i = 0; i < 4; ++i)
        tile[ty + i * 8][tx] = in[(size_t)(r0 + ty + i * 8) * Cn + c0 + tx];
    __syncthreads();
#pragma unroll
    for (int i = 0; i < 4; ++i)
        out[(size_t)(c0 + ty + i * 8) * R + r0 + tx] = f2bf(tile[tx][ty + i * 8]);
}

// ---------- RoPE tables (fp64 once, tiny) ----------
__global__ void rope_table(float* __restrict__ tabc, float* __restrict__ tabs) {
    int idx = blockIdx.x * 256 + threadIdx.x;
    if (idx >= T_ * 32) return;
    int t = idx >> 5, j = idx & 31;
    double invf = pow(10000.0, -(double)j / 32.0);
    double th = (double)t * invf;
    tabc[idx] = (float)cos(th);
    tabs[idx] = (float)sin(th);
}

// ---------- V transpose: Vh[m][d1024] -> Vt[bh][d][t] ----------
__global__ void v_transpose(const u16* __restrict__ Vh, u16* __restrict__ Vt) {
    __shared__ u16 tile[64 * 68];                      // row stride 68 u16 = 136 B
    const int tid = threadIdx.x;
    const int bh = blockIdx.y, b = bh >> 4, h = bh & 15;
    const int t0 = blockIdx.x * 64;
    {
        int lr = tid >> 2;                             // t-row 0..63
        int lc = tid & 3;
        const u16* src = Vh + ((size_t)(b * T_ + t0 + lr)) * DIM_ + h * HD_;
#pragma unroll
        for (int j = 0; j < 4; ++j) {
            int c = (lc + j * 4) * 4;                  // u16 col, 8B chunks
            *(uint2*)&tile[lr * 68 + c] = *(const uint2*)(src + c);
        }
    }
    __syncthreads();
    {
        int d2 = tid >> 3, tseg = tid & 7;             // dword col 0..31, t-seg 0..7
        u16 lo8[8], hi8[8];
#pragma unroll
        for (int j = 0; j < 8; ++j) {
            unsigned w = *(const unsigned*)&tile[(tseg * 8 + j) * 68 + d2 * 2];
            lo8[j] = (u16)(w & 0xffffu);
            hi8[j] = (u16)(w >> 16);
        }
        size_t ob = ((size_t)bh * HD_ + 2 * d2) * T_ + t0 + tseg * 8;
        *(uint4*)(Vt + ob) = *(const uint4*)lo8;
        *(uint4*)(Vt + ob + T_) = *(const uint4*)hi8;
    }
}

// ---------- qkv GEMM with fused RoPE/split, LDS-coalesced epilogue ----------
// One 128x128 tile per block (round-7 structure: VGPR 128, 0 conflicts).
// Launched with 16 KB dynamic LDS deadweight -> 48 KB/block -> 3 blocks/CU,
// so the 1536-block grid runs exactly 2 full epochs (no 75%-fill tail).
__global__ __launch_bounds__(256) void gemm_qkv(const u16* __restrict__ A,
                                                const u16* __restrict__ Bt,
                                                const float* __restrict__ tabc,
                                                const float* __restrict__ tabs,
                                                u16* __restrict__ Qo,
                                                u16* __restrict__ Ko,
                                                u16* __restrict__ Vh) {
    __shared__ __align__(16) u16 smem[2 * 128 * 64];   // Asl | Bsl ; reused as Es[128][128]
    u16* Asl = smem;
    u16* Bsl = smem + 128 * 64;
    const int tid = threadIdx.x;
    const int wave = tid >> 6, lane = tid & 63;
    const int ln15 = lane & 15, quad = lane >> 4;
    const int m0 = blockIdx.y * 128, n0 = blockIdx.x * 128;
    const int wm = (wave & 1) * 64, wn = (wave >> 1) * 64;
    const int l8 = lane & 7, ld8 = lane >> 3;
    const int sgc = (l8 ^ ld8) * 8;                    // swizzled source col (u16)
    const int K = DIM_;

    floatx4 acc[4][4] = {};

    for (int k0 = 0; k0 < K; k0 += 64) {
#pragma unroll
        for (int it = 0; it < 4; ++it) {
            int rb = wave * 32 + it * 8;
            async_load16(A  + (size_t)(m0 + rb + ld8) * K + k0 + sgc, &Asl[rb * 64]);
            async_load16(Bt + (size_t)(n0 + rb + ld8) * K + k0 + sgc, &Bsl[rb * 64]);
        }
        __syncthreads();
#pragma unroll
        for (int kk = 0; kk < 64; kk += 32) {
            const int c4 = kk >> 3;                    // 0 or 4
            short8 af[4], bfm[4];
#pragma unroll
            for (int i = 0; i < 4; ++i) {
                int row = wm + i * 16 + ln15;
                af[i] = *(const short8*)&Asl[row * 64 + (((c4 + quad) ^ (row & 7)) << 3)];
            }
#pragma unroll
            for (int jj = 0; jj < 4; ++jj) {
                int row = wn + jj * 16 + ln15;
                bfm[jj] = *(const short8*)&Bsl[row * 64 + (((c4 + quad) ^ (row & 7)) << 3)];
            }
#pragma unroll
            for (int i = 0; i < 4; ++i)
#pragma unroll
                for (int jj = 0; jj < 4; ++jj)
                    acc[i][jj] = __builtin_amdgcn_mfma_f32_16x16x32_bf16(
                        af[i], bfm[jj], acc[i][jj], 0, 0, 0);
        }
        __syncthreads();                               // also frees smem for epilogue
    }

    // ---- epilogue: acc -> Es (bf16, chunk-swizzled) -> coalesced stores ----
    u16* Es = smem;
    const int sel = n0 >> 10;                          // 0=q, 1=k, 2=v
    auto es_put = [&](int row, int col, u16 v) {
        int c = col >> 3;
        int pc = (c & 8) | ((c & 7) ^ (row & 7));
        Es[row * 128 + pc * 8 + (col & 7)] = v;
    };
    if (sel == 2) {
#pragma unroll
        for (int i = 0; i < 4; ++i)
#pragma unroll
            for (int jj = 0; jj < 4; ++jj)
#pragma unroll
                for (int r = 0; r < 4; ++r)
                    es_put(wm + i * 16 + quad * 4 + r, wn + jj * 16 + ln15,
                           f2bf(acc[i][jj][r]));
    } else {
        const float scale = sel ? 1.0f : 0.125f * LOG2E;
#pragma unroll
        for (int i = 0; i < 4; ++i)
#pragma unroll
            for (int jjl = 0; jjl < 2; ++jjl) {
                int j = jjl * 16 + ln15;               // d in [0,32)
#pragma unroll
                for (int r = 0; r < 4; ++r) {
                    int row = wm + i * 16 + quad * 4 + r;
                    int t = (m0 + row) & (T_ - 1);
                    float cs = tabc[t * 32 + j], sn = tabs[t * 32 + j];
                    float xl = acc[i][jjl][r], xh = acc[i][jjl + 2][r];
                    es_put(row, wn + j,      f2bf((xl * cs - xh * sn) * scale));
                    es_put(row, wn + j + 32, f2bf((xh * cs + xl * sn) * scale));
                }
            }
    }
    __syncthreads();
    const int bb = m0 >> 11;
    u16* outqk = (sel == 1) ? Ko : Qo;
#pragma unroll
    for (int k = 0; k < 8; ++k) {
        int cid = tid + k * 256;                       // 0..2047
        int row = cid >> 4, c = cid & 15;              // logical chunk 0..15
        int pc = (c & 8) | ((c & 7) ^ (row & 7));
        uint4 v = *(const uint4*)&Es[row * 128 + pc * 8];
        if (sel == 2) {
            *(uint4*)&Vh[(size_t)(m0 + row) * DIM_ + (n0 & 1023) + c * 8] = v;
        } else {
            int h = ((n0 & 1023) >> 6) + (c >> 3);
            int d = (c & 7) * 8;
            int t = (m0 + row) & (T_ - 1);
            *(uint4*)&outqk[((size_t)(bb * NH_ + h) * T_ + t) * HD_ + d] = v;
        }
    }
}

// ---------- generic 128x128 GEMM (used for out-proj), swizzled LDS ----------
__global__ __launch_bounds__(256) void gemm_bt_f32(const u16* __restrict__ A,
                                                   const u16* __restrict__ Bt,
                                                   float* __restrict__ C,
                                                   int M, int N, int K) {
    __shared__ __align__(16) u16 Asl[128 * 64];
    __shared__ __align__(16) u16 Bsl[128 * 64];
    const int tid = threadIdx.x;
    const int wave = tid >> 6, lane = tid & 63;
    const int ln15 = lane & 15, quad = lane >> 4;
    const int m0 = blockIdx.y * 128, n0 = blockIdx.x * 128;
    const int wm = (wave & 1) * 64, wn = (wave >> 1) * 64;
    const int l8 = lane & 7, ld8 = lane >> 3;
    const int sgc = (l8 ^ ld8) * 8;

    floatx4 acc[4][4] = {};

    for (int k0 = 0; k0 < K; k0 += 64) {
#pragma unroll
        for (int it = 0; it < 4; ++it) {
            int rb = wave * 32 + it * 8;
            async_load16(A  + (size_t)(m0 + rb + ld8) * K + k0 + sgc, &Asl[rb * 64]);
            async_load16(Bt + (size_t)(n0 + rb + ld8) * K + k0 + sgc, &Bsl[rb * 64]);
        }
        __syncthreads();
#pragma unroll
        for (int kk = 0; kk < 64; kk += 32) {
            const int c4 = kk >> 3;
            short8 af[4], bfm[4];
#pragma unroll
            for (int i = 0; i < 4; ++i) {
                int row = wm + i * 16 + ln15;
                af[i] = *(const short8*)&Asl[row * 64 + (((c4 + quad) ^ (row & 7)) << 3)];
            }
#pragma unroll
            for (int jj = 0; jj < 4; ++jj) {
                int row = wn + jj * 16 + ln15;
                bfm[jj] = *(const short8*)&Bsl[row * 64 + (((c4 + quad) ^ (row & 7)) << 3)];
            }
#pragma unroll
            for (int i = 0; i < 4; ++i)
#pragma unroll
                for (int jj = 0; jj < 4; ++jj)
                    acc[i][jj] = __builtin_amdgcn_mfma_f32_16x16x32_bf16(
                        af[i], bfm[jj], acc[i][jj], 0, 0, 0);
        }
        __syncthreads();
    }
#pragma unroll
    for (int i = 0; i < 4; ++i)
#pragma unroll
        for (int jj = 0; jj < 4; ++jj)
#pragma unroll
            for (int r = 0; r < 4; ++r) {
                int m = m0 + wm + i * 16 + quad * 4 + r;
                int n = n0 + wn + jj * 16 + ln15;
                C[(size_t)m * N + n] = acc[i][jj][r];
            }
}

// ---------- flash attention, uniform-work pairing, no-max softmax, dbuf K/V ----
__global__ __launch_bounds__(256, 4) void attn_kernel(const u16* __restrict__ Q,
                                                      const u16* __restrict__ Kh,
                                                      const u16* __restrict__ Vt,
                                                      u16* __restrict__ Y) {
    __shared__ __align__(16) u16 Kl[2][64 * 64];
    __shared__ __align__(16) u16 Vl[2][64 * 64];
    __shared__ __align__(16) u16 Pl[4][16 * 64];
    const int tid = threadIdx.x, wave = tid >> 6, lane = tid & 63;
    const int ln15 = lane & 15, quad = lane >> 4;
    const int p = blockIdx.x;                          // pair index 0..15
    const int bh = blockIdx.y;
    const int b = bh >> 4, h = bh & 15;
    const int l8 = lane & 7, ld8 = lane >> 3;
    const int sgc = l8 ^ ld8;                          // swizzled source chunk

    const u16* kbase = Kh + (size_t)bh * T_ * HD_;
    const u16* vbase = Vt + (size_t)bh * HD_ * T_;
    const short8 ones = {0x3F80, 0x3F80, 0x3F80, 0x3F80,
                         0x3F80, 0x3F80, 0x3F80, 0x3F80};
    const int srow = wave * 16;

#pragma unroll
    for (int half = 0; half < 2; ++half) {
        const int tidx = half ? p : (31 - p);          // q-tile index 0..31
        const int q0 = tidx * 64;
        const int bm = q0 + srow;

        const u16* qp = Q + ((size_t)bh * T_ + bm + ln15) * HD_;
        short8 qf0 = *(const short8*)(qp + quad * 8);
        short8 qf1 = *(const short8*)(qp + 32 + quad * 8);

        floatx4 o[5] = {};                             // 0..3 = d-cols, 4 = rowsum

        __syncthreads();                               // buffers free from prev half
#pragma unroll
        for (int it = 0; it < 2; ++it) {
            int r = srow + it * 8;
            async_load16(kbase + (size_t)(r + ld8) * HD_ + sgc * 8, &Kl[0][r * 64]);
            async_load16(vbase + (size_t)(r + ld8) * T_ + sgc * 8, &Vl[0][r * 64]);
        }

        for (int kt = 0; kt <= tidx; ++kt) {
            const int cur = kt & 1;
            __syncthreads();                           // publishes tile kt
            if (kt < tidx) {                           // prefetch kt+1 (overlaps)
                const int kn = (kt + 1) * 64;
#pragma unroll
                for (int it = 0; it < 2; ++it) {
                    int r = srow + it * 8;
                    async_load16(kbase + (size_t)(kn + r + ld8) * HD_ + sgc * 8,
                                 &Kl[cur ^ 1][r * 64]);
                    async_load16(vbase + (size_t)(r + ld8) * T_ + kn + sgc * 8,
                                 &Vl[cur ^ 1][r * 64]);
                }
            }
            floatx4 s[4] = {};
#pragma unroll
            for (int nt = 0; nt < 4; ++nt) {
                int row = nt * 16 + ln15;
                short8 kf0 = *(const short8*)&Kl[cur][row * 64 + ((quad ^ (row & 7)) << 3)];
                short8 kf1 = *(const short8*)&Kl[cur][row * 64 + (((4 + quad) ^ (row & 7)) << 3)];
                s[nt] = __builtin_amdgcn_mfma_f32_16x16x32_bf16(qf0, kf0, s[nt], 0, 0, 0);
                s[nt] = __builtin_amdgcn_mfma_f32_16x16x32_bf16(qf1, kf1, s[nt], 0, 0, 0);
            }
            if (kt == tidx) {                          // diagonal tile: causal mask
#pragma unroll
                for (int nt = 0; nt < 4; ++nt) {
                    int key = nt * 16 + ln15, lim = srow + quad * 4;
#pragma unroll
                    for (int r = 0; r < 4; ++r)
                        s[nt][r] = (key > lim + r) ? 0.f : fexp2(s[nt][r]);
                }
            } else {
#pragma unroll
                for (int nt = 0; nt < 4; ++nt)
#pragma unroll
                    for (int r = 0; r < 4; ++r) s[nt][r] = fexp2(s[nt][r]);
            }
            u16* pw = Pl[wave];
#pragma unroll
            for (int nt = 0; nt < 4; ++nt) {
                int kc = nt * 2 + (ln15 >> 3), k7 = ln15 & 7;
#pragma unroll
                for (int r = 0; r < 4; ++r) {
                    int row = quad * 4 + r;
                    pw[row * 64 + ((kc ^ (row & 7)) << 3) + k7] = f2bf(s[nt][r]);
                }
            }
            short8 pf0 = *(const short8*)&pw[ln15 * 64 + ((quad ^ (ln15 & 7)) << 3)];
            short8 pf1 = *(const short8*)&pw[ln15 * 64 + (((4 + quad) ^ (ln15 & 7)) << 3)];
#pragma unroll
            for (int nt = 0; nt < 4; ++nt) {
                int row = nt * 16 + ln15;
                short8 vf0 = *(const short8*)&Vl[cur][row * 64 + ((quad ^ (row & 7)) << 3)];
                short8 vf1 = *(const short8*)&Vl[cur][row * 64 + (((4 + quad) ^ (row & 7)) << 3)];
                o[nt] = __builtin_amdgcn_mfma_f32_16x16x32_bf16(pf0, vf0, o[nt], 0, 0, 0);
                o[nt] = __builtin_amdgcn_mfma_f32_16x16x32_bf16(pf1, vf1, o[nt], 0, 0, 0);
            }
            o[4] = __builtin_amdgcn_mfma_f32_16x16x32_bf16(pf0, ones, o[4], 0, 0, 0);
            o[4] = __builtin_amdgcn_mfma_f32_16x16x32_bf16(pf1, ones, o[4], 0, 0, 0);
        }
#pragma unroll
        for (int r = 0; r < 4; ++r) {
            float inv = 1.f / o[4][r];
            int row = bm + quad * 4 + r;
            u16* yp = Y + ((size_t)(b * T_ + row)) * DIM_ + h * HD_;
#pragma unroll
            for (int nt = 0; nt < 4; ++nt)
                yp[nt * 16 + ln15] = f2bf(o[nt][r] * inv);
        }
    }
}

// ---------- launch ----------
extern "C" void kernel_launch(void* const* d_in, const int* in_sizes, int n_in,
                              void* d_out, int out_size, void* d_ws, size_t ws_size,
                              hipStream_t stream) {
    const float* x     = (const float*)d_in[0];
    const float* Wqkv  = (const float*)d_in[1];
    const float* Wproj = (const float*)d_in[2];
    float* out = (float*)d_out;
    char* ws = (char*)d_ws;

    const size_t SZ_XB  = (size_t)M_ * DIM_ * 2;       // 16 MB
    const size_t SZ_WQT = (size_t)NQKV * DIM_ * 2;     // 6 MB
    const size_t SZ_WPT = (size_t)DIM_ * DIM_ * 2;     // 2 MB
    const size_t SZ_Q   = SZ_XB;                       // 16 MB each: Q,K,Vh,Vt
    const size_t SZ_TAB = (size_t)T_ * 32 * 4;         // 256 KB

    u16*   xb   = (u16*)(ws);
    u16*   wqt  = (u16*)(ws + SZ_XB);
    u16*   wpt  = (u16*)(ws + SZ_XB + SZ_WQT);
    u16*   qb   = (u16*)(ws + SZ_XB + SZ_WQT + SZ_WPT);
    u16*   kb   = (u16*)(ws + SZ_XB + SZ_WQT + SZ_WPT + SZ_Q);
    u16*   vhb  = (u16*)(ws + SZ_XB + SZ_WQT + SZ_WPT + 2 * SZ_Q);
    u16*   vtb  = (u16*)(ws + SZ_XB + SZ_WQT + SZ_WPT + 3 * SZ_Q);
    float* tabc = (float*)(ws + SZ_XB + SZ_WQT + SZ_WPT + 4 * SZ_Q);
    float* tabs = (float*)(ws + SZ_XB + SZ_WQT + SZ_WPT + 4 * SZ_Q + SZ_TAB);
    u16*   yb   = xb;                                  // reuse xb after qkv GEMM

    rope_table<<<(T_ * 32 + 255) / 256, 256, 0, stream>>>(tabc, tabs);
    cvt_x<<<(M_ * DIM_ / 4) / 256, 256, 0, stream>>>(x, xb);
    transpose_cvt<<<dim3(NQKV / 32, DIM_ / 32), dim3(32, 8), 0, stream>>>(Wqkv, wqt, DIM_, NQKV);
    transpose_cvt<<<dim3(DIM_ / 32, DIM_ / 32), dim3(32, 8), 0, stream>>>(Wproj, wpt, DIM_, DIM_);
    // 16 KB dynamic LDS deadweight: 48 KB/block -> 3 blocks/CU -> 1536 blocks
    // = exactly 2 full epochs (removes the 75%-fill tail measured in r7).
    gemm_qkv<<<dim3(NQKV / 128, M_ / 128), 256, 16384, stream>>>(xb, wqt, tabc, tabs, qb, kb, vhb);
    v_transpose<<<dim3(T_ / 64, B_ * NH_), 256, 0, stream>>>(vhb, vtb);
    attn_kernel<<<dim3(16, B_ * NH_), 256, 0, stream>>>(qb, kb, vtb, yb);
    gemm_bt_f32<<<dim3(DIM_ / 128, M_ / 128), 256, 0, stream>>>(yb, wpt, out, M_, DIM_, DIM_);
}